// Round 3
// baseline (1795.659 us; speedup 1.0000x reference)
//
#include <hip/hip_runtime.h>
#include <hip/hip_bf16.h>

// HeteroGCN: 2-layer, 3-relation GraphConv (norm='both') on MI355X.
// Build phase (bucketed counting-sort CSR, replaces atomic csrfill):
//   K1 count:   LDS histogram of dst-buckets (dst>>6) + deg_out atomics
//   K2 scan:    exclusive prefix of bucket counts -> bbase/bcursor
//   K3 part:    partition edges into bucket staging (packed src*64|dst&63)
//   K4 build:   per-bucket LDS histogram+scan -> offsets/deg_in/rs_in/rs_out,
//               scatter src into contiguous CSR segment
// Layer phase:
//   per r: GEMM1 (x @ W1[r]) * rs_out -> feat ; AGG1 CSR gather -> h1 (+bias,ReLU)
//   GEMM2 (wave/node) -> feat2 ; AGG2 gather + bias -> out

#define N_REL 3
#define IN_F 256
#define HID_F 128
#define NBMAX 1568  // buckets of 64 nodes: ceil(100000/64)=1563 <= 1568

// ---------------- K1: bucket count + deg_out ----------------
__global__ __launch_bounds__(256) void HeteroGCN_count_kernel(
    const int* __restrict__ edges, unsigned* __restrict__ deg_out,
    unsigned* __restrict__ bcount, int N, int E, int NB) {
  __shared__ unsigned hist[NBMAX];
  int r = blockIdx.y;
  for (int i = threadIdx.x; i < NB; i += 256) hist[i] = 0u;
  __syncthreads();
  const int* ep = edges + (size_t)r * 2 * E;
  int stride = gridDim.x * 256;
  for (int e = blockIdx.x * 256 + threadIdx.x; e < E; e += stride) {
    int src = ep[e];
    int dst = ep[E + e];
    atomicAdd(&hist[dst >> 6], 1u);
    atomicAdd(&deg_out[r * N + src], 1u);
  }
  __syncthreads();
  for (int i = threadIdx.x; i < NB; i += 256) {
    unsigned h = hist[i];
    if (h) atomicAdd(&bcount[r * NB + i], h);
  }
}

// ---------------- K2: exclusive scan of bucket counts ----------------
__global__ __launch_bounds__(256) void HeteroGCN_scan_kernel(
    const unsigned* __restrict__ bcount, unsigned* __restrict__ bbase,
    unsigned* __restrict__ bcursor, int NB) {
  __shared__ unsigned wsum[4];
  __shared__ unsigned carry;
  int r = blockIdx.x;
  int tid = threadIdx.x;
  int lane = tid & 63;
  int wid = tid >> 6;
  if (tid == 0) carry = 0u;
  __syncthreads();
  for (int chunk = 0; chunk < NB; chunk += 256) {
    int i = chunk + tid;
    unsigned v = (i < NB) ? bcount[r * NB + i] : 0u;
    unsigned pre = v;
    #pragma unroll
    for (int d = 1; d < 64; d <<= 1) {
      unsigned t = __shfl_up(pre, (unsigned)d, 64);
      if (lane >= d) pre += t;
    }
    if (lane == 63) wsum[wid] = pre;
    __syncthreads();
    unsigned woff = 0;
    for (int w = 0; w < wid; ++w) woff += wsum[w];
    unsigned exc = carry + woff + pre - v;
    if (i < NB) {
      bbase[r * NB + i] = exc;
      bcursor[r * NB + i] = exc;
    }
    __syncthreads();
    if (tid == 0) carry += wsum[0] + wsum[1] + wsum[2] + wsum[3];
    __syncthreads();
  }
}

// ---------------- K3: partition into bucket staging ----------------
__global__ __launch_bounds__(256) void HeteroGCN_part_kernel(
    const int* __restrict__ edges, const unsigned* __restrict__ bbase,
    unsigned* __restrict__ bcursor, unsigned* __restrict__ staging,
    int E, int NB) {
  int e = blockIdx.x * 256 + threadIdx.x;
  int r = blockIdx.y;
  if (e >= E) return;
  const int* ep = edges + (size_t)r * 2 * E;
  int src = ep[e];
  int dst = ep[E + e];
  int b = dst >> 6;
  unsigned slot = atomicAdd(&bcursor[r * NB + b], 1u);
  staging[(size_t)r * E + slot] = ((unsigned)src << 6) | ((unsigned)dst & 63u);
}

// ---------------- K4: per-bucket CSR build + node metadata ----------------
__global__ __launch_bounds__(256) void HeteroGCN_build_kernel(
    const unsigned* __restrict__ staging, const unsigned* __restrict__ bbase,
    const unsigned* __restrict__ bcount, const unsigned* __restrict__ deg_out,
    int* __restrict__ csr_src, int* __restrict__ offsets,
    unsigned* __restrict__ deg_in, float* __restrict__ rs_in,
    float* __restrict__ rs_out, int N, int E, int NB) {
  __shared__ unsigned hist[64];
  __shared__ unsigned cur[64];
  int b = blockIdx.x;
  int r = blockIdx.y;
  int tid = threadIdx.x;
  unsigned base = bbase[r * NB + b];
  unsigned cnt = bcount[r * NB + b];
  if (tid < 64) hist[tid] = 0u;
  __syncthreads();
  const unsigned* sp = staging + (size_t)r * E + base;
  for (unsigned i = tid; i < cnt; i += 256) atomicAdd(&hist[sp[i] & 63u], 1u);
  __syncthreads();
  if (tid < 64) {
    unsigned h = hist[tid];
    unsigned pre = h;
    #pragma unroll
    for (int d = 1; d < 64; d <<= 1) {
      unsigned t = __shfl_up(pre, (unsigned)d, 64);
      if (tid >= d) pre += t;
    }
    unsigned exc = pre - h;
    cur[tid] = exc;
    int n = b * 64 + tid;
    if (n < N) {
      size_t gi = (size_t)r * N + n;
      deg_in[gi] = h;
      rs_in[gi] = rsqrtf((float)max(h, 1u));
      offsets[gi] = (int)(base + exc);
      rs_out[gi] = rsqrtf((float)max(deg_out[gi], 1u));
    }
  }
  __syncthreads();
  int* cp = csr_src + (size_t)r * E + base;
  for (unsigned i = tid; i < cnt; i += 256) {
    unsigned rec = sp[i];
    unsigned slot = atomicAdd(&cur[rec & 63u], 1u);
    cp[slot] = (int)(rec >> 6);
  }
}

// ---------------- GEMM1: feat = (x @ W) * rs_out, M x 256 @ 256 x 128 ----------
// BM=64, BN=128, BK=64. 256 threads; thread computes 4 rows x 8 cols.
__global__ __launch_bounds__(256) void HeteroGCN_gemm1_kernel(
    const float* __restrict__ x, const float* __restrict__ W,
    const float* __restrict__ rs_out, float* __restrict__ feat, int M) {
  __shared__ float As[64][68];
  __shared__ float Bs[64][128];
  int tid = threadIdx.x;
  int block_row = blockIdx.x * 64;
  int rg = tid >> 4;
  int cg = tid & 15;
  int row0 = rg * 4;
  int colA = cg * 4;
  float acc[4][8] = {};
  for (int k0 = 0; k0 < IN_F; k0 += 64) {
    #pragma unroll
    for (int i = 0; i < 4; ++i) {
      int f4 = tid + i * 256;
      int rr = f4 >> 4;
      int cc = (f4 & 15) << 2;
      int grow = block_row + rr;
      float4 v = make_float4(0.f, 0.f, 0.f, 0.f);
      if (grow < M) v = *(const float4*)(x + (size_t)grow * IN_F + k0 + cc);
      *(float4*)(&As[rr][cc]) = v;
    }
    #pragma unroll
    for (int i = 0; i < 8; ++i) {
      int f4 = tid + i * 256;
      int rr = f4 >> 5;
      int cc = (f4 & 31) << 2;
      *(float4*)(&Bs[rr][cc]) = *(const float4*)(W + (size_t)(k0 + rr) * HID_F + cc);
    }
    __syncthreads();
    #pragma unroll
    for (int kk = 0; kk < 64; ++kk) {
      float a[4];
      #pragma unroll
      for (int i = 0; i < 4; ++i) a[i] = As[row0 + i][kk];
      float4 b0 = *(const float4*)(&Bs[kk][colA]);
      float4 b1 = *(const float4*)(&Bs[kk][64 + colA]);
      #pragma unroll
      for (int i = 0; i < 4; ++i) {
        acc[i][0] += a[i] * b0.x; acc[i][1] += a[i] * b0.y;
        acc[i][2] += a[i] * b0.z; acc[i][3] += a[i] * b0.w;
        acc[i][4] += a[i] * b1.x; acc[i][5] += a[i] * b1.y;
        acc[i][6] += a[i] * b1.z; acc[i][7] += a[i] * b1.w;
      }
    }
    __syncthreads();
  }
  #pragma unroll
  for (int i = 0; i < 4; ++i) {
    int grow = block_row + row0 + i;
    if (grow < M) {
      float s = rs_out[grow];
      float4 v0 = make_float4(acc[i][0] * s, acc[i][1] * s, acc[i][2] * s, acc[i][3] * s);
      float4 v1 = make_float4(acc[i][4] * s, acc[i][5] * s, acc[i][6] * s, acc[i][7] * s);
      *(float4*)(feat + (size_t)grow * HID_F + colA) = v0;
      *(float4*)(feat + (size_t)grow * HID_F + 64 + colA) = v1;
    }
  }
}

// ---------------- AGG1: h1 accumulation via CSR gather ----------------
// 256 threads = 2 nodes x 128 feats; 4 independent loads in flight.
__global__ __launch_bounds__(256) void HeteroGCN_agg1_kernel(
    const float* __restrict__ feat, const int* __restrict__ csr_r,
    const int* __restrict__ offsets_r, const unsigned* __restrict__ deg_in_r,
    const float* __restrict__ rs_in_r, const float* __restrict__ b1,
    float* __restrict__ h1, int N, int rel) {
  int half = threadIdx.x >> 7;
  int f = threadIdx.x & 127;
  int n = blockIdx.x * 2 + half;
  if (n >= N) return;
  int off = offsets_r[n];
  int cnt = (int)deg_in_r[n];
  const int* sp = csr_r + off;
  float a0 = 0.f, a1 = 0.f, a2 = 0.f, a3 = 0.f;
  int i = 0;
  for (; i + 3 < cnt; i += 4) {
    int s0 = sp[i], s1 = sp[i + 1], s2 = sp[i + 2], s3 = sp[i + 3];
    a0 += feat[(size_t)s0 * HID_F + f];
    a1 += feat[(size_t)s1 * HID_F + f];
    a2 += feat[(size_t)s2 * HID_F + f];
    a3 += feat[(size_t)s3 * HID_F + f];
  }
  for (; i < cnt; ++i) a0 += feat[(size_t)sp[i] * HID_F + f];
  float v = ((a0 + a1) + (a2 + a3)) * rs_in_r[n];
  size_t oi = (size_t)n * HID_F + f;
  if (rel == 0) {
    h1[oi] = v;
  } else if (rel == 1) {
    h1[oi] += v;
  } else {
    float b = b1[f] + b1[HID_F + f] + b1[2 * HID_F + f];
    h1[oi] = fmaxf(h1[oi] + v + b, 0.f);
  }
}

// ---------------- GEMM2: feat2[r][n][c] = (h1[n].W2[r][:,c]) * rs_out[r][n] ----
__global__ __launch_bounds__(256) void HeteroGCN_gemm2_kernel(
    const float* __restrict__ h1, const float* __restrict__ W2,
    const float* __restrict__ rs_out, float* __restrict__ feat2, int N) {
  int wid = (blockIdx.x * blockDim.x + threadIdx.x) >> 6;
  int lane = threadIdx.x & 63;
  if (wid >= N) return;
  float2 h = *(const float2*)(h1 + (size_t)wid * HID_F + lane * 2);
  float p[6];
  #pragma unroll
  for (int r = 0; r < 3; ++r) {
    #pragma unroll
    for (int c = 0; c < 2; ++c) {
      float w0 = W2[((size_t)r * HID_F + lane * 2) * 2 + c];
      float w1 = W2[((size_t)r * HID_F + lane * 2 + 1) * 2 + c];
      p[r * 2 + c] = h.x * w0 + h.y * w1;
    }
  }
  #pragma unroll
  for (int o = 32; o > 0; o >>= 1) {
    #pragma unroll
    for (int q = 0; q < 6; ++q) p[q] += __shfl_xor(p[q], o, 64);
  }
  if (lane == 0) {
    #pragma unroll
    for (int q = 0; q < 6; ++q) {
      int r = q >> 1, c = q & 1;
      feat2[((size_t)r * N + wid) * 2 + c] = p[q] * rs_out[r * N + wid];
    }
  }
}

// ---------------- AGG2: out[n][c] = sum_r rs_in * sum_src feat2 + bias ---------
__global__ __launch_bounds__(256) void HeteroGCN_agg2_kernel(
    const float* __restrict__ feat2, const int* __restrict__ csr_src,
    const int* __restrict__ offsets, const unsigned* __restrict__ deg_in,
    const float* __restrict__ rs_in, const float* __restrict__ b2,
    float* __restrict__ out, int N, int E) {
  int n = blockIdx.x * blockDim.x + threadIdx.x;
  if (n >= N) return;
  float o0 = 0.f, o1 = 0.f;
  #pragma unroll
  for (int r = 0; r < 3; ++r) {
    int off = offsets[r * N + n];
    int cnt = (int)deg_in[r * N + n];
    const int* sp = csr_src + (size_t)r * E + off;
    const float* fp = feat2 + (size_t)r * N * 2;
    float a0 = 0.f, a1 = 0.f, c0 = 0.f, c1 = 0.f;
    int i = 0;
    for (; i + 1 < cnt; i += 2) {
      int s0 = sp[i], s1 = sp[i + 1];
      float2 f0 = *(const float2*)(fp + (size_t)s0 * 2);
      float2 f1 = *(const float2*)(fp + (size_t)s1 * 2);
      a0 += f0.x; a1 += f0.y;
      c0 += f1.x; c1 += f1.y;
    }
    if (i < cnt) {
      float2 f0 = *(const float2*)(fp + (size_t)sp[i] * 2);
      a0 += f0.x; a1 += f0.y;
    }
    float ri = rs_in[r * N + n];
    o0 += (a0 + c0) * ri + b2[r * 2 + 0];
    o1 += (a1 + c1) * ri + b2[r * 2 + 1];
  }
  *(float2*)(out + (size_t)n * 2) = make_float2(o0, o1);
}

extern "C" void kernel_launch(void* const* d_in, const int* in_sizes, int n_in,
                              void* d_out, int out_size, void* d_ws, size_t ws_size,
                              hipStream_t stream) {
  const float* x = (const float*)d_in[0];
  const int* edges = (const int*)d_in[1];
  const float* W1 = (const float*)d_in[2];
  const float* b1 = (const float*)d_in[3];
  const float* W2 = (const float*)d_in[4];
  const float* b2 = (const float*)d_in[5];
  float* out = (float*)d_out;

  const int N = in_sizes[0] / IN_F;          // 100000
  const int E = in_sizes[1] / (N_REL * 2);   // 1600000
  const int NB = (N + 63) >> 6;              // 1563 dst-buckets of 64 nodes

  // workspace layout (256B aligned); staging aliases feat (build precedes use)
  char* ws = (char*)d_ws;
  size_t p = 0;
  auto take = [&](size_t b) { size_t o = p; p += (b + 255) & ~(size_t)255; return o; };
  size_t deg_out_off = take((size_t)N_REL * N * 4);       // memset region start
  size_t bcount_off  = take((size_t)N_REL * NBMAX * 4);   // memset region end
  size_t bbase_off   = take((size_t)N_REL * NBMAX * 4);
  size_t bcursor_off = take((size_t)N_REL * NBMAX * 4);
  size_t deg_in_off  = take((size_t)N_REL * N * 4);
  size_t rs_out_off  = take((size_t)N_REL * N * 4);
  size_t rs_in_off   = take((size_t)N_REL * N * 4);
  size_t offsets_off = take((size_t)N_REL * N * 4);
  size_t csr_off     = take((size_t)N_REL * E * 4);
  size_t feat_off    = take((size_t)N * HID_F * 4);       // staging aliases this
  size_t h1_off      = take((size_t)N * HID_F * 4);
  size_t feat2_off   = take((size_t)N_REL * N * 2 * 4);
  (void)ws_size;

  unsigned* deg_out = (unsigned*)(ws + deg_out_off);
  unsigned* bcount  = (unsigned*)(ws + bcount_off);
  unsigned* bbase   = (unsigned*)(ws + bbase_off);
  unsigned* bcursor = (unsigned*)(ws + bcursor_off);
  unsigned* deg_in  = (unsigned*)(ws + deg_in_off);
  float* rs_out = (float*)(ws + rs_out_off);
  float* rs_in  = (float*)(ws + rs_in_off);
  int* offsets  = (int*)(ws + offsets_off);
  int* csr_src  = (int*)(ws + csr_off);
  float* feat   = (float*)(ws + feat_off);
  unsigned* staging = (unsigned*)(ws + feat_off);  // alias: 19.2MB < 51.2MB
  float* h1     = (float*)(ws + h1_off);
  float* feat2  = (float*)(ws + feat2_off);

  // zero deg_out + bcount (contiguous region)
  hipMemsetAsync(ws + deg_out_off, 0,
                 bcount_off + (size_t)N_REL * NBMAX * 4 - deg_out_off, stream);

  dim3 blk(256);
  // K1: bucket histogram + deg_out
  HeteroGCN_count_kernel<<<dim3(512, N_REL), blk, 0, stream>>>(
      edges, deg_out, bcount, N, E, NB);
  // K2: bucket prefix scan
  HeteroGCN_scan_kernel<<<dim3(N_REL), blk, 0, stream>>>(bcount, bbase, bcursor, NB);
  // K3: partition into staging
  HeteroGCN_part_kernel<<<dim3((E + 255) / 256, N_REL), blk, 0, stream>>>(
      edges, bbase, bcursor, staging, E, NB);
  // K4: per-bucket CSR + node metadata
  HeteroGCN_build_kernel<<<dim3(NB, N_REL), blk, 0, stream>>>(
      staging, bbase, bcount, deg_out, csr_src, offsets, deg_in, rs_in, rs_out,
      N, E, NB);

  // layer 1, relation by relation (feat buffer reused; staging dead by now)
  for (int r = 0; r < N_REL; ++r) {
    HeteroGCN_gemm1_kernel<<<dim3((N + 63) / 64), blk, 0, stream>>>(
        x, W1 + (size_t)r * IN_F * HID_F, rs_out + (size_t)r * N, feat, N);
    HeteroGCN_agg1_kernel<<<dim3((N + 1) / 2), blk, 0, stream>>>(
        feat, csr_src + (size_t)r * E, offsets + (size_t)r * N,
        deg_in + (size_t)r * N, rs_in + (size_t)r * N, b1, h1, N, r);
  }

  // layer 2
  HeteroGCN_gemm2_kernel<<<dim3((N * 64 + 255) / 256), blk, 0, stream>>>(
      h1, W2, rs_out, feat2, N);
  HeteroGCN_agg2_kernel<<<dim3((N + 255) / 256), blk, 0, stream>>>(
      feat2, csr_src, offsets, deg_in, rs_in, b2, out, N, E);
}

// Round 6
// 1245.966 us; speedup vs baseline: 1.4412x; 1.4412x over previous
//
#include <hip/hip_runtime.h>
#include <hip/hip_bf16.h>

// HeteroGCN: 2-layer, 3-relation GraphConv (norm='both') on MI355X.
// Build phase (LDS tile-sort counting CSR — coalesced staging writes):
//   K1 count: LDS histogram of dst super-buckets (dst>>11) + deg_out atomics
//   K2 scan:  exclusive prefix of super-bucket counts -> sbbase/scursor
//   K3 part:  per 2048-edge tile: LDS 49-bin multisplit, bin-ordered LDS
//             staging, run-coalesced global writes (src<<11|dst&2047)
//   K4 build: per super-bucket (2048 nodes): LDS histogram + block scan ->
//             offsets/deg_in/rs_in/rs_out; scatter src into contiguous
//             L2-resident CSR segment
// Layer phase:
//   per r: GEMM1 (x @ W1[r]) * rs_out -> feat ; AGG1 CSR gather -> h1 (+bias,ReLU)
//   GEMM2 (wave/node) -> feat2 ; AGG2 gather + bias -> out

#define N_REL 3
#define IN_F 256
#define HID_F 128
#define SB_BITS 11
#define SB_SIZE 2048   // nodes per super-bucket
#define NSBMAX 64      // ceil(100000/2048)=49 <= 64
#define TILE 2048      // edges per part-tile

// ---------------- K1: super-bucket count + deg_out ----------------
__global__ __launch_bounds__(256) void HeteroGCN_count_kernel(
    const int* __restrict__ edges, unsigned* __restrict__ deg_out,
    unsigned* __restrict__ bcount, int N, int E, int NS) {
  __shared__ unsigned hist[NSBMAX];
  int r = blockIdx.y;
  if (threadIdx.x < NSBMAX) hist[threadIdx.x] = 0u;
  __syncthreads();
  const int* ep = edges + (size_t)r * 2 * E;
  int stride = gridDim.x * 256;
  for (int e = blockIdx.x * 256 + threadIdx.x; e < E; e += stride) {
    int src = ep[e];
    int dst = ep[E + e];
    atomicAdd(&hist[dst >> SB_BITS], 1u);
    atomicAdd(&deg_out[r * N + src], 1u);
  }
  __syncthreads();
  if (threadIdx.x < (unsigned)NS) {
    unsigned h = hist[threadIdx.x];
    if (h) atomicAdd(&bcount[r * NSBMAX + threadIdx.x], h);
  }
}

// ---------------- K2: exclusive scan of super-bucket counts ----------------
__global__ __launch_bounds__(64) void HeteroGCN_scan_kernel(
    const unsigned* __restrict__ bcount, unsigned* __restrict__ sbbase,
    unsigned* __restrict__ scursor, int NS) {
  int r = blockIdx.x;
  int t = threadIdx.x;
  unsigned v = (t < NS) ? bcount[r * NSBMAX + t] : 0u;
  unsigned pre = v;
  #pragma unroll
  for (int d = 1; d < 64; d <<= 1) {
    unsigned tt = __shfl_up(pre, (unsigned)d, 64);
    if (t >= d) pre += tt;
  }
  if (t < NS) {
    sbbase[r * NSBMAX + t] = pre - v;
    scursor[r * NSBMAX + t] = pre - v;
  }
}

// ---------------- K3: tile-sort partition into staging ----------------
// One block = one 2048-edge tile. LDS multisplit -> run-coalesced writes.
__global__ __launch_bounds__(256) void HeteroGCN_part_kernel(
    const int* __restrict__ edges, unsigned* __restrict__ scursor,
    unsigned* __restrict__ staging, int E, int NS) {
  __shared__ unsigned hist[NSBMAX];
  __shared__ unsigned toff[NSBMAX];
  __shared__ unsigned gbase[NSBMAX];
  __shared__ unsigned ordb[TILE];
  __shared__ unsigned addrb[TILE];
  int r = blockIdx.y;
  const int* ep = edges + (size_t)r * 2 * E;
  int t0 = blockIdx.x * TILE;
  int nt = min(TILE, E - t0);
  if (threadIdx.x < NSBMAX) hist[threadIdx.x] = 0u;
  __syncthreads();
  int sbk[8];
  unsigned rkk[8], pkk[8];
  #pragma unroll 8
  for (int k = 0; k < 8; ++k) {
    int ii = k * 256 + (int)threadIdx.x;
    sbk[k] = -1;
    if (ii < nt) {
      int i = t0 + ii;
      int src = ep[i];
      int dst = ep[E + i];
      int sb = dst >> SB_BITS;
      rkk[k] = atomicAdd(&hist[sb], 1u);
      pkk[k] = ((unsigned)src << SB_BITS) | ((unsigned)dst & (SB_SIZE - 1u));
      sbk[k] = sb;
    }
  }
  __syncthreads();
  if (threadIdx.x < 64) {
    unsigned v = ((int)threadIdx.x < NS) ? hist[threadIdx.x] : 0u;
    unsigned pre = v;
    #pragma unroll
    for (int d = 1; d < 64; d <<= 1) {
      unsigned tt = __shfl_up(pre, (unsigned)d, 64);
      if ((int)threadIdx.x >= d) pre += tt;
    }
    if ((int)threadIdx.x < NS) {
      toff[threadIdx.x] = pre - v;
      gbase[threadIdx.x] =
          v ? atomicAdd(&scursor[r * NSBMAX + threadIdx.x], v) : 0u;
    }
  }
  __syncthreads();
  #pragma unroll 8
  for (int k = 0; k < 8; ++k) {
    if (sbk[k] >= 0) {
      unsigned pos = toff[sbk[k]] + rkk[k];
      ordb[pos] = pkk[k];
      addrb[pos] = gbase[sbk[k]] + rkk[k];
    }
  }
  __syncthreads();
  unsigned* stg = staging + (size_t)r * E;
  for (int ii = threadIdx.x; ii < nt; ii += 256) {
    stg[addrb[ii]] = ordb[ii];  // piecewise-consecutive addresses
  }
}

// ---------------- K4: per-super-bucket CSR build + node metadata ----------------
__global__ __launch_bounds__(256) void HeteroGCN_build_kernel(
    const unsigned* __restrict__ staging, const unsigned* __restrict__ sbbase,
    const unsigned* __restrict__ bcount, const unsigned* __restrict__ deg_out,
    int* __restrict__ csr_src, int* __restrict__ offsets,
    unsigned* __restrict__ deg_in, float* __restrict__ rs_in,
    float* __restrict__ rs_out, int N, int E) {
  __shared__ unsigned hist[SB_SIZE];  // histogram -> exclusive offsets -> cursors
  __shared__ unsigned wtot[4];
  int s = blockIdx.x;
  int r = blockIdx.y;
  int tid = threadIdx.x;
  int lane = tid & 63;
  int wid = tid >> 6;
  unsigned base = sbbase[r * NSBMAX + s];
  unsigned cnt = bcount[r * NSBMAX + s];
  for (int i = tid; i < SB_SIZE; i += 256) hist[i] = 0u;
  __syncthreads();
  const unsigned* sp = staging + (size_t)r * E + base;
  for (unsigned i = tid; i < cnt; i += 256)
    atomicAdd(&hist[sp[i] & (SB_SIZE - 1u)], 1u);
  __syncthreads();
  // block exclusive scan over hist[2048], 8 values per thread
  unsigned v[8], lsum = 0;
  #pragma unroll 8
  for (int k = 0; k < 8; ++k) {
    v[k] = hist[tid * 8 + k];
    lsum += v[k];
  }
  unsigned pre = lsum;
  #pragma unroll
  for (int d = 1; d < 64; d <<= 1) {
    unsigned tt = __shfl_up(pre, (unsigned)d, 64);
    if (lane >= d) pre += tt;
  }
  if (lane == 63) wtot[wid] = pre;
  __syncthreads();
  unsigned woff = 0;
  for (int w = 0; w < wid; ++w) woff += wtot[w];
  unsigned run = woff + pre - lsum;  // exclusive offset of this thread's first node
  #pragma unroll 8
  for (int k = 0; k < 8; ++k) {
    int node = s * SB_SIZE + tid * 8 + k;
    if (node < N) {
      size_t gi = (size_t)r * N + node;
      deg_in[gi] = v[k];
      rs_in[gi] = rsqrtf((float)max(v[k], 1u));
      offsets[gi] = (int)(base + run);
      rs_out[gi] = rsqrtf((float)max(deg_out[gi], 1u));
    }
    hist[tid * 8 + k] = run;  // becomes scatter cursor
    run += v[k];
  }
  __syncthreads();
  int* cp = csr_src + (size_t)r * E + base;
  for (unsigned i = tid; i < cnt; i += 256) {
    unsigned rec = sp[i];
    unsigned slot = atomicAdd(&hist[rec & (SB_SIZE - 1u)], 1u);
    cp[slot] = (int)(rec >> SB_BITS);  // contiguous L2-resident segment
  }
}

// ---------------- GEMM1: feat = (x @ W) * rs_out, M x 256 @ 256 x 128 ----------
__global__ __launch_bounds__(256) void HeteroGCN_gemm1_kernel(
    const float* __restrict__ x, const float* __restrict__ W,
    const float* __restrict__ rs_out, float* __restrict__ feat, int M) {
  __shared__ float As[64][68];
  __shared__ float Bs[64][128];
  int tid = threadIdx.x;
  int block_row = blockIdx.x * 64;
  int rg = tid >> 4;
  int cg = tid & 15;
  int row0 = rg * 4;
  int colA = cg * 4;
  float acc[4][8] = {};
  for (int k0 = 0; k0 < IN_F; k0 += 64) {
    #pragma unroll
    for (int i = 0; i < 4; ++i) {
      int f4 = tid + i * 256;
      int rr = f4 >> 4;
      int cc = (f4 & 15) << 2;
      int grow = block_row + rr;
      float4 vv = make_float4(0.f, 0.f, 0.f, 0.f);
      if (grow < M) vv = *(const float4*)(x + (size_t)grow * IN_F + k0 + cc);
      *(float4*)(&As[rr][cc]) = vv;
    }
    #pragma unroll
    for (int i = 0; i < 8; ++i) {
      int f4 = tid + i * 256;
      int rr = f4 >> 5;
      int cc = (f4 & 31) << 2;
      *(float4*)(&Bs[rr][cc]) = *(const float4*)(W + (size_t)(k0 + rr) * HID_F + cc);
    }
    __syncthreads();
    #pragma unroll
    for (int kk = 0; kk < 64; ++kk) {
      float a[4];
      #pragma unroll
      for (int i = 0; i < 4; ++i) a[i] = As[row0 + i][kk];
      float4 b0 = *(const float4*)(&Bs[kk][colA]);
      float4 b1 = *(const float4*)(&Bs[kk][64 + colA]);
      #pragma unroll
      for (int i = 0; i < 4; ++i) {
        acc[i][0] += a[i] * b0.x; acc[i][1] += a[i] * b0.y;
        acc[i][2] += a[i] * b0.z; acc[i][3] += a[i] * b0.w;
        acc[i][4] += a[i] * b1.x; acc[i][5] += a[i] * b1.y;
        acc[i][6] += a[i] * b1.z; acc[i][7] += a[i] * b1.w;
      }
    }
    __syncthreads();
  }
  #pragma unroll
  for (int i = 0; i < 4; ++i) {
    int grow = block_row + row0 + i;
    if (grow < M) {
      float s = rs_out[grow];
      float4 v0 = make_float4(acc[i][0] * s, acc[i][1] * s, acc[i][2] * s, acc[i][3] * s);
      float4 v1 = make_float4(acc[i][4] * s, acc[i][5] * s, acc[i][6] * s, acc[i][7] * s);
      *(float4*)(feat + (size_t)grow * HID_F + colA) = v0;
      *(float4*)(feat + (size_t)grow * HID_F + 64 + colA) = v1;
    }
  }
}

// ---------------- AGG1: h1 accumulation via CSR gather ----------------
__global__ __launch_bounds__(256) void HeteroGCN_agg1_kernel(
    const float* __restrict__ feat, const int* __restrict__ csr_r,
    const int* __restrict__ offsets_r, const unsigned* __restrict__ deg_in_r,
    const float* __restrict__ rs_in_r, const float* __restrict__ b1,
    float* __restrict__ h1, int N, int rel) {
  int half = threadIdx.x >> 7;
  int f = threadIdx.x & 127;
  int n = blockIdx.x * 2 + half;
  if (n >= N) return;
  int off = offsets_r[n];
  int cnt = (int)deg_in_r[n];
  const int* sp = csr_r + off;
  float a0 = 0.f, a1 = 0.f, a2 = 0.f, a3 = 0.f;
  int i = 0;
  for (; i + 3 < cnt; i += 4) {
    int s0 = sp[i], s1 = sp[i + 1], s2 = sp[i + 2], s3 = sp[i + 3];
    a0 += feat[(size_t)s0 * HID_F + f];
    a1 += feat[(size_t)s1 * HID_F + f];
    a2 += feat[(size_t)s2 * HID_F + f];
    a3 += feat[(size_t)s3 * HID_F + f];
  }
  for (; i < cnt; ++i) a0 += feat[(size_t)sp[i] * HID_F + f];
  float v = ((a0 + a1) + (a2 + a3)) * rs_in_r[n];
  size_t oi = (size_t)n * HID_F + f;
  if (rel == 0) {
    h1[oi] = v;
  } else if (rel == 1) {
    h1[oi] += v;
  } else {
    float b = b1[f] + b1[HID_F + f] + b1[2 * HID_F + f];
    h1[oi] = fmaxf(h1[oi] + v + b, 0.f);
  }
}

// ---------------- GEMM2: feat2[r][n][c] = (h1[n].W2[r][:,c]) * rs_out[r][n] ----
__global__ __launch_bounds__(256) void HeteroGCN_gemm2_kernel(
    const float* __restrict__ h1, const float* __restrict__ W2,
    const float* __restrict__ rs_out, float* __restrict__ feat2, int N) {
  int wid = (blockIdx.x * blockDim.x + threadIdx.x) >> 6;
  int lane = threadIdx.x & 63;
  if (wid >= N) return;
  float2 h = *(const float2*)(h1 + (size_t)wid * HID_F + lane * 2);
  float p[6];
  #pragma unroll
  for (int r = 0; r < 3; ++r) {
    #pragma unroll
    for (int c = 0; c < 2; ++c) {
      float w0 = W2[((size_t)r * HID_F + lane * 2) * 2 + c];
      float w1 = W2[((size_t)r * HID_F + lane * 2 + 1) * 2 + c];
      p[r * 2 + c] = h.x * w0 + h.y * w1;
    }
  }
  #pragma unroll
  for (int o = 32; o > 0; o >>= 1) {
    #pragma unroll
    for (int q = 0; q < 6; ++q) p[q] += __shfl_xor(p[q], o, 64);
  }
  if (lane == 0) {
    #pragma unroll
    for (int q = 0; q < 6; ++q) {
      int r = q >> 1, c = q & 1;
      feat2[((size_t)r * N + wid) * 2 + c] = p[q] * rs_out[r * N + wid];
    }
  }
}

// ---------------- AGG2: out[n][c] = sum_r rs_in * sum_src feat2 + bias ---------
__global__ __launch_bounds__(256) void HeteroGCN_agg2_kernel(
    const float* __restrict__ feat2, const int* __restrict__ csr_src,
    const int* __restrict__ offsets, const unsigned* __restrict__ deg_in,
    const float* __restrict__ rs_in, const float* __restrict__ b2,
    float* __restrict__ out, int N, int E) {
  int n = blockIdx.x * blockDim.x + threadIdx.x;
  if (n >= N) return;
  float o0 = 0.f, o1 = 0.f;
  #pragma unroll
  for (int r = 0; r < 3; ++r) {
    int off = offsets[r * N + n];
    int cnt = (int)deg_in[r * N + n];
    const int* sp = csr_src + (size_t)r * E + off;
    const float* fp = feat2 + (size_t)r * N * 2;
    float a0 = 0.f, a1 = 0.f, c0 = 0.f, c1 = 0.f;
    int i = 0;
    for (; i + 1 < cnt; i += 2) {
      int s0 = sp[i], s1 = sp[i + 1];
      float2 f0 = *(const float2*)(fp + (size_t)s0 * 2);
      float2 f1 = *(const float2*)(fp + (size_t)s1 * 2);
      a0 += f0.x; a1 += f0.y;
      c0 += f1.x; c1 += f1.y;
    }
    if (i < cnt) {
      float2 f0 = *(const float2*)(fp + (size_t)sp[i] * 2);
      a0 += f0.x; a1 += f0.y;
    }
    float ri = rs_in[r * N + n];
    o0 += (a0 + c0) * ri + b2[r * 2 + 0];
    o1 += (a1 + c1) * ri + b2[r * 2 + 1];
  }
  *(float2*)(out + (size_t)n * 2) = make_float2(o0, o1);
}

extern "C" void kernel_launch(void* const* d_in, const int* in_sizes, int n_in,
                              void* d_out, int out_size, void* d_ws, size_t ws_size,
                              hipStream_t stream) {
  const float* x = (const float*)d_in[0];
  const int* edges = (const int*)d_in[1];
  const float* W1 = (const float*)d_in[2];
  const float* b1 = (const float*)d_in[3];
  const float* W2 = (const float*)d_in[4];
  const float* b2 = (const float*)d_in[5];
  float* out = (float*)d_out;

  const int N = in_sizes[0] / IN_F;          // 100000
  const int E = in_sizes[1] / (N_REL * 2);   // 1600000
  const int NS = (N + SB_SIZE - 1) >> SB_BITS;  // 49 super-buckets

  // workspace layout (256B aligned); staging aliases feat (build precedes use)
  char* ws = (char*)d_ws;
  size_t p = 0;
  auto take = [&](size_t b) { size_t o = p; p += (b + 255) & ~(size_t)255; return o; };
  size_t deg_out_off = take((size_t)N_REL * N * 4);       // memset region start
  size_t bcount_off  = take((size_t)N_REL * NSBMAX * 4);  // memset region end
  size_t sbbase_off  = take((size_t)N_REL * NSBMAX * 4);
  size_t scursor_off = take((size_t)N_REL * NSBMAX * 4);
  size_t deg_in_off  = take((size_t)N_REL * N * 4);
  size_t rs_out_off  = take((size_t)N_REL * N * 4);
  size_t rs_in_off   = take((size_t)N_REL * N * 4);
  size_t offsets_off = take((size_t)N_REL * N * 4);
  size_t csr_off     = take((size_t)N_REL * E * 4);
  size_t feat_off    = take((size_t)N * HID_F * 4);       // staging aliases this
  size_t h1_off      = take((size_t)N * HID_F * 4);
  size_t feat2_off   = take((size_t)N_REL * N * 2 * 4);
  (void)ws_size;

  unsigned* deg_out = (unsigned*)(ws + deg_out_off);
  unsigned* bcount  = (unsigned*)(ws + bcount_off);
  unsigned* sbbase  = (unsigned*)(ws + sbbase_off);
  unsigned* scursor = (unsigned*)(ws + scursor_off);
  unsigned* deg_in  = (unsigned*)(ws + deg_in_off);
  float* rs_out = (float*)(ws + rs_out_off);
  float* rs_in  = (float*)(ws + rs_in_off);
  int* offsets  = (int*)(ws + offsets_off);
  int* csr_src  = (int*)(ws + csr_off);
  float* feat   = (float*)(ws + feat_off);
  unsigned* staging = (unsigned*)(ws + feat_off);  // alias: 19.2MB < 51.2MB
  float* h1     = (float*)(ws + h1_off);
  float* feat2  = (float*)(ws + feat2_off);

  // zero deg_out + bcount (contiguous region)
  hipMemsetAsync(ws + deg_out_off, 0,
                 bcount_off + (size_t)N_REL * NSBMAX * 4 - deg_out_off, stream);

  dim3 blk(256);
  HeteroGCN_count_kernel<<<dim3(512, N_REL), blk, 0, stream>>>(
      edges, deg_out, bcount, N, E, NS);
  HeteroGCN_scan_kernel<<<dim3(N_REL), dim3(64), 0, stream>>>(
      bcount, sbbase, scursor, NS);
  HeteroGCN_part_kernel<<<dim3((E + TILE - 1) / TILE, N_REL), blk, 0, stream>>>(
      edges, scursor, staging, E, NS);
  HeteroGCN_build_kernel<<<dim3(NS, N_REL), blk, 0, stream>>>(
      staging, sbbase, bcount, deg_out, csr_src, offsets, deg_in, rs_in, rs_out,
      N, E);

  // layer 1, relation by relation (feat buffer reused; staging dead by now)
  for (int r = 0; r < N_REL; ++r) {
    HeteroGCN_gemm1_kernel<<<dim3((N + 63) / 64), blk, 0, stream>>>(
        x, W1 + (size_t)r * IN_F * HID_F, rs_out + (size_t)r * N, feat, N);
    HeteroGCN_agg1_kernel<<<dim3((N + 1) / 2), blk, 0, stream>>>(
        feat, csr_src + (size_t)r * E, offsets + (size_t)r * N,
        deg_in + (size_t)r * N, rs_in + (size_t)r * N, b1, h1, N, r);
  }

  // layer 2
  HeteroGCN_gemm2_kernel<<<dim3((N * 64 + 255) / 256), blk, 0, stream>>>(
      h1, W2, rs_out, feat2, N);
  HeteroGCN_agg2_kernel<<<dim3((N + 255) / 256), blk, 0, stream>>>(
      feat2, csr_src, offsets, deg_in, rs_in, b2, out, N, E);
}

// Round 7
// 1112.127 us; speedup vs baseline: 1.6146x; 1.1203x over previous
//
#include <hip/hip_runtime.h>
#include <hip/hip_bf16.h>

// HeteroGCN: 2-layer, 3-relation GraphConv (norm='both') on MI355X.
// Build phase (all scatter/histogram work LDS-local; global writes coalesced —
// measured: random 4B global atomics/stores cost ~32B HBM write-through each):
//   K1 count:  LDS 49-bin hist of dst>>11 AND src>>11 (no per-node atomics)
//   K2 scan2:  exclusive prefix of 6 bucket-count rows (dst x3, src x3)
//   K3 part:   per 2048-edge tile: LDS multisplit on BOTH keys; coalesced
//              staging writes (dst: src<<11|dst&2047 u32; src: src&2047 u16)
//   K4 build:  per dst-super-bucket: LDS hist+scan -> offsets/deg_in/rs_in;
//              scatter src into contiguous L2-resident CSR segment
//   K5 degout: per src-super-bucket: LDS hist -> rs_out (coalesced write)
// Layer phase:
//   per r: GEMM1 (x @ W1[r]) * rs_out -> feat ; AGG1 CSR gather -> h1 (+bias,ReLU)
//   GEMM2 (wave/node) -> feat2 ; AGG2 gather + bias -> out

#define N_REL 3
#define IN_F 256
#define HID_F 128
#define SB_BITS 11
#define SB_SIZE 2048   // nodes per super-bucket
#define NSBMAX 64      // ceil(100000/2048)=49 <= 64
#define TILE 2048      // edges per part-tile

// ---------------- K1: dual 49-bin bucket count (dst + src) ----------------
__global__ __launch_bounds__(256) void HeteroGCN_count_kernel(
    const int* __restrict__ edges, unsigned* __restrict__ bcount2,
    int E, int NS) {
  __shared__ unsigned hd[NSBMAX];
  __shared__ unsigned hs[NSBMAX];
  int r = blockIdx.y;
  if (threadIdx.x < NSBMAX) { hd[threadIdx.x] = 0u; hs[threadIdx.x] = 0u; }
  __syncthreads();
  const int* ep = edges + (size_t)r * 2 * E;
  int stride = gridDim.x * 256;
  for (int e = blockIdx.x * 256 + threadIdx.x; e < E; e += stride) {
    int src = ep[e];
    int dst = ep[E + e];
    atomicAdd(&hd[dst >> SB_BITS], 1u);
    atomicAdd(&hs[src >> SB_BITS], 1u);
  }
  __syncthreads();
  if (threadIdx.x < (unsigned)NS) {
    unsigned h = hd[threadIdx.x];
    if (h) atomicAdd(&bcount2[r * NSBMAX + threadIdx.x], h);
    h = hs[threadIdx.x];
    if (h) atomicAdd(&bcount2[(N_REL + r) * NSBMAX + threadIdx.x], h);
  }
}

// ---------------- K2: exclusive scan of 6 bucket-count rows ----------------
__global__ __launch_bounds__(64) void HeteroGCN_scan_kernel(
    const unsigned* __restrict__ bcount2, unsigned* __restrict__ sbbase2,
    unsigned* __restrict__ scursor2, int NS) {
  int row = blockIdx.x;  // 0..2*N_REL-1
  int t = threadIdx.x;
  unsigned v = (t < NS) ? bcount2[row * NSBMAX + t] : 0u;
  unsigned pre = v;
  #pragma unroll
  for (int d = 1; d < 64; d <<= 1) {
    unsigned tt = __shfl_up(pre, (unsigned)d, 64);
    if (t >= d) pre += tt;
  }
  if (t < NS) {
    sbbase2[row * NSBMAX + t] = pre - v;
    scursor2[row * NSBMAX + t] = pre - v;
  }
}

// ---------------- K3: tile-sort partition into dst + src stagings ----------------
__global__ __launch_bounds__(256) void HeteroGCN_part_kernel(
    const int* __restrict__ edges, unsigned* __restrict__ scursor2,
    unsigned* __restrict__ staging_dst, unsigned short* __restrict__ staging_src,
    int E, int NS) {
  __shared__ unsigned hd[NSBMAX], hs[NSBMAX];
  __shared__ unsigned toffd[NSBMAX], toffs[NSBMAX];
  __shared__ unsigned gbd[NSBMAX], gbs[NSBMAX];
  __shared__ unsigned ordb[TILE];
  __shared__ unsigned addrb[TILE];
  __shared__ unsigned short srcw[TILE];
  __shared__ unsigned saddr[TILE];
  int r = blockIdx.y;
  const int* ep = edges + (size_t)r * 2 * E;
  int t0 = blockIdx.x * TILE;
  int nt = min(TILE, E - t0);
  if (threadIdx.x < NSBMAX) { hd[threadIdx.x] = 0u; hs[threadIdx.x] = 0u; }
  __syncthreads();
  int sbk[8];
  unsigned rkk[8], pkk[8], rks[8];
  #pragma unroll 8
  for (int k = 0; k < 8; ++k) {
    int ii = k * 256 + (int)threadIdx.x;
    sbk[k] = -1;
    if (ii < nt) {
      int i = t0 + ii;
      int src = ep[i];
      int dst = ep[E + i];
      int sb = dst >> SB_BITS;
      rkk[k] = atomicAdd(&hd[sb], 1u);
      rks[k] = atomicAdd(&hs[src >> SB_BITS], 1u);
      pkk[k] = ((unsigned)src << SB_BITS) | ((unsigned)dst & (SB_SIZE - 1u));
      sbk[k] = sb;
    }
  }
  __syncthreads();
  {
    int w = threadIdx.x >> 6, l = threadIdx.x & 63;
    if (w < 2) {
      unsigned* hh = w ? hs : hd;
      unsigned* tf = w ? toffs : toffd;
      unsigned* gb = w ? gbs : gbd;
      int row = w ? (N_REL + r) : r;
      unsigned v = (l < NS) ? hh[l] : 0u;
      unsigned pre = v;
      #pragma unroll
      for (int d = 1; d < 64; d <<= 1) {
        unsigned tt = __shfl_up(pre, (unsigned)d, 64);
        if (l >= d) pre += tt;
      }
      if (l < NS) {
        tf[l] = pre - v;
        gb[l] = v ? atomicAdd(&scursor2[row * NSBMAX + l], v) : 0u;
      }
    }
  }
  __syncthreads();
  #pragma unroll 8
  for (int k = 0; k < 8; ++k) {
    if (sbk[k] >= 0) {
      unsigned pos = toffd[sbk[k]] + rkk[k];
      ordb[pos] = pkk[k];
      addrb[pos] = gbd[sbk[k]] + rkk[k];
      int sb2 = (int)(pkk[k] >> 22);          // src >> 11
      unsigned pos2 = toffs[sb2] + rks[k];
      srcw[pos2] = (unsigned short)((pkk[k] >> SB_BITS) & (SB_SIZE - 1u));
      saddr[pos2] = gbs[sb2] + rks[k];
    }
  }
  __syncthreads();
  unsigned* stg = staging_dst + (size_t)r * E;
  unsigned short* sst = staging_src + (size_t)r * E;
  for (int ii = threadIdx.x; ii < nt; ii += 256) {
    stg[addrb[ii]] = ordb[ii];   // piecewise-consecutive addresses
    sst[saddr[ii]] = srcw[ii];
  }
}

// ---------------- K4: per-dst-super-bucket CSR build + node metadata ----------
__global__ __launch_bounds__(256) void HeteroGCN_build_kernel(
    const unsigned* __restrict__ staging_dst, const unsigned* __restrict__ sbbase2,
    const unsigned* __restrict__ bcount2, int* __restrict__ csr_src,
    int* __restrict__ offsets, unsigned* __restrict__ deg_in,
    float* __restrict__ rs_in, int N, int E) {
  __shared__ unsigned hist[SB_SIZE];  // histogram -> exclusive offsets -> cursors
  __shared__ unsigned wtot[4];
  int s = blockIdx.x;
  int r = blockIdx.y;
  int tid = threadIdx.x;
  int lane = tid & 63;
  int wid = tid >> 6;
  unsigned base = sbbase2[r * NSBMAX + s];
  unsigned cnt = bcount2[r * NSBMAX + s];
  for (int i = tid; i < SB_SIZE; i += 256) hist[i] = 0u;
  __syncthreads();
  const unsigned* sp = staging_dst + (size_t)r * E + base;
  for (unsigned i = tid; i < cnt; i += 256)
    atomicAdd(&hist[sp[i] & (SB_SIZE - 1u)], 1u);
  __syncthreads();
  // block exclusive scan over hist[2048], 8 values per thread
  unsigned v[8], lsum = 0;
  #pragma unroll 8
  for (int k = 0; k < 8; ++k) {
    v[k] = hist[tid * 8 + k];
    lsum += v[k];
  }
  unsigned pre = lsum;
  #pragma unroll
  for (int d = 1; d < 64; d <<= 1) {
    unsigned tt = __shfl_up(pre, (unsigned)d, 64);
    if (lane >= d) pre += tt;
  }
  if (lane == 63) wtot[wid] = pre;
  __syncthreads();
  unsigned woff = 0;
  for (int w = 0; w < wid; ++w) woff += wtot[w];
  unsigned run = woff + pre - lsum;  // exclusive offset of this thread's first node
  #pragma unroll 8
  for (int k = 0; k < 8; ++k) {
    int node = s * SB_SIZE + tid * 8 + k;
    if (node < N) {
      size_t gi = (size_t)r * N + node;
      deg_in[gi] = v[k];
      rs_in[gi] = rsqrtf((float)max(v[k], 1u));
      offsets[gi] = (int)(base + run);
    }
    hist[tid * 8 + k] = run;  // becomes scatter cursor
    run += v[k];
  }
  __syncthreads();
  int* cp = csr_src + (size_t)r * E + base;
  for (unsigned i = tid; i < cnt; i += 256) {
    unsigned rec = sp[i];
    unsigned slot = atomicAdd(&hist[rec & (SB_SIZE - 1u)], 1u);
    cp[slot] = (int)(rec >> SB_BITS);  // contiguous L2-resident segment
  }
}

// ---------------- K5: per-src-super-bucket deg_out histogram -> rs_out --------
__global__ __launch_bounds__(256) void HeteroGCN_degout_kernel(
    const unsigned short* __restrict__ staging_src,
    const unsigned* __restrict__ sbbase2, const unsigned* __restrict__ bcount2,
    float* __restrict__ rs_out, int N, int E) {
  __shared__ unsigned hist[SB_SIZE];
  int s = blockIdx.x;
  int r = blockIdx.y;
  int tid = threadIdx.x;
  unsigned base = sbbase2[(N_REL + r) * NSBMAX + s];
  unsigned cnt = bcount2[(N_REL + r) * NSBMAX + s];
  for (int i = tid; i < SB_SIZE; i += 256) hist[i] = 0u;
  __syncthreads();
  const unsigned short* sp = staging_src + (size_t)r * E + base;
  for (unsigned i = tid; i < cnt; i += 256) atomicAdd(&hist[sp[i]], 1u);
  __syncthreads();
  for (int i = tid; i < SB_SIZE; i += 256) {
    int node = s * SB_SIZE + i;
    if (node < N)
      rs_out[(size_t)r * N + node] = rsqrtf((float)max(hist[i], 1u));
  }
}

// ---------------- GEMM1: feat = (x @ W) * rs_out, M x 256 @ 256 x 128 ----------
__global__ __launch_bounds__(256) void HeteroGCN_gemm1_kernel(
    const float* __restrict__ x, const float* __restrict__ W,
    const float* __restrict__ rs_out, float* __restrict__ feat, int M) {
  __shared__ float As[64][68];
  __shared__ float Bs[64][128];
  int tid = threadIdx.x;
  int block_row = blockIdx.x * 64;
  int rg = tid >> 4;
  int cg = tid & 15;
  int row0 = rg * 4;
  int colA = cg * 4;
  float acc[4][8] = {};
  for (int k0 = 0; k0 < IN_F; k0 += 64) {
    #pragma unroll
    for (int i = 0; i < 4; ++i) {
      int f4 = tid + i * 256;
      int rr = f4 >> 4;
      int cc = (f4 & 15) << 2;
      int grow = block_row + rr;
      float4 vv = make_float4(0.f, 0.f, 0.f, 0.f);
      if (grow < M) vv = *(const float4*)(x + (size_t)grow * IN_F + k0 + cc);
      *(float4*)(&As[rr][cc]) = vv;
    }
    #pragma unroll
    for (int i = 0; i < 8; ++i) {
      int f4 = tid + i * 256;
      int rr = f4 >> 5;
      int cc = (f4 & 31) << 2;
      *(float4*)(&Bs[rr][cc]) = *(const float4*)(W + (size_t)(k0 + rr) * HID_F + cc);
    }
    __syncthreads();
    #pragma unroll
    for (int kk = 0; kk < 64; ++kk) {
      float a[4];
      #pragma unroll
      for (int i = 0; i < 4; ++i) a[i] = As[row0 + i][kk];
      float4 b0 = *(const float4*)(&Bs[kk][colA]);
      float4 b1 = *(const float4*)(&Bs[kk][64 + colA]);
      #pragma unroll
      for (int i = 0; i < 4; ++i) {
        acc[i][0] += a[i] * b0.x; acc[i][1] += a[i] * b0.y;
        acc[i][2] += a[i] * b0.z; acc[i][3] += a[i] * b0.w;
        acc[i][4] += a[i] * b1.x; acc[i][5] += a[i] * b1.y;
        acc[i][6] += a[i] * b1.z; acc[i][7] += a[i] * b1.w;
      }
    }
    __syncthreads();
  }
  #pragma unroll
  for (int i = 0; i < 4; ++i) {
    int grow = block_row + row0 + i;
    if (grow < M) {
      float s = rs_out[grow];
      float4 v0 = make_float4(acc[i][0] * s, acc[i][1] * s, acc[i][2] * s, acc[i][3] * s);
      float4 v1 = make_float4(acc[i][4] * s, acc[i][5] * s, acc[i][6] * s, acc[i][7] * s);
      *(float4*)(feat + (size_t)grow * HID_F + colA) = v0;
      *(float4*)(feat + (size_t)grow * HID_F + 64 + colA) = v1;
    }
  }
}

// ---------------- AGG1: h1 accumulation via CSR gather ----------------
__global__ __launch_bounds__(256) void HeteroGCN_agg1_kernel(
    const float* __restrict__ feat, const int* __restrict__ csr_r,
    const int* __restrict__ offsets_r, const unsigned* __restrict__ deg_in_r,
    const float* __restrict__ rs_in_r, const float* __restrict__ b1,
    float* __restrict__ h1, int N, int rel) {
  int half = threadIdx.x >> 7;
  int f = threadIdx.x & 127;
  int n = blockIdx.x * 2 + half;
  if (n >= N) return;
  int off = offsets_r[n];
  int cnt = (int)deg_in_r[n];
  const int* sp = csr_r + off;
  float a0 = 0.f, a1 = 0.f, a2 = 0.f, a3 = 0.f;
  int i = 0;
  for (; i + 3 < cnt; i += 4) {
    int s0 = sp[i], s1 = sp[i + 1], s2 = sp[i + 2], s3 = sp[i + 3];
    a0 += feat[(size_t)s0 * HID_F + f];
    a1 += feat[(size_t)s1 * HID_F + f];
    a2 += feat[(size_t)s2 * HID_F + f];
    a3 += feat[(size_t)s3 * HID_F + f];
  }
  for (; i < cnt; ++i) a0 += feat[(size_t)sp[i] * HID_F + f];
  float v = ((a0 + a1) + (a2 + a3)) * rs_in_r[n];
  size_t oi = (size_t)n * HID_F + f;
  if (rel == 0) {
    h1[oi] = v;
  } else if (rel == 1) {
    h1[oi] += v;
  } else {
    float b = b1[f] + b1[HID_F + f] + b1[2 * HID_F + f];
    h1[oi] = fmaxf(h1[oi] + v + b, 0.f);
  }
}

// ---------------- GEMM2: feat2[r][n][c] = (h1[n].W2[r][:,c]) * rs_out[r][n] ----
__global__ __launch_bounds__(256) void HeteroGCN_gemm2_kernel(
    const float* __restrict__ h1, const float* __restrict__ W2,
    const float* __restrict__ rs_out, float* __restrict__ feat2, int N) {
  int wid = (blockIdx.x * blockDim.x + threadIdx.x) >> 6;
  int lane = threadIdx.x & 63;
  if (wid >= N) return;
  float2 h = *(const float2*)(h1 + (size_t)wid * HID_F + lane * 2);
  float p[6];
  #pragma unroll
  for (int r = 0; r < 3; ++r) {
    #pragma unroll
    for (int c = 0; c < 2; ++c) {
      float w0 = W2[((size_t)r * HID_F + lane * 2) * 2 + c];
      float w1 = W2[((size_t)r * HID_F + lane * 2 + 1) * 2 + c];
      p[r * 2 + c] = h.x * w0 + h.y * w1;
    }
  }
  #pragma unroll
  for (int o = 32; o > 0; o >>= 1) {
    #pragma unroll
    for (int q = 0; q < 6; ++q) p[q] += __shfl_xor(p[q], o, 64);
  }
  if (lane == 0) {
    #pragma unroll
    for (int q = 0; q < 6; ++q) {
      int r = q >> 1, c = q & 1;
      feat2[((size_t)r * N + wid) * 2 + c] = p[q] * rs_out[r * N + wid];
    }
  }
}

// ---------------- AGG2: out[n][c] = sum_r rs_in * sum_src feat2 + bias ---------
__global__ __launch_bounds__(256) void HeteroGCN_agg2_kernel(
    const float* __restrict__ feat2, const int* __restrict__ csr_src,
    const int* __restrict__ offsets, const unsigned* __restrict__ deg_in,
    const float* __restrict__ rs_in, const float* __restrict__ b2,
    float* __restrict__ out, int N, int E) {
  int n = blockIdx.x * blockDim.x + threadIdx.x;
  if (n >= N) return;
  float o0 = 0.f, o1 = 0.f;
  #pragma unroll
  for (int r = 0; r < 3; ++r) {
    int off = offsets[r * N + n];
    int cnt = (int)deg_in[r * N + n];
    const int* sp = csr_src + (size_t)r * E + off;
    const float* fp = feat2 + (size_t)r * N * 2;
    float a0 = 0.f, a1 = 0.f, c0 = 0.f, c1 = 0.f;
    int i = 0;
    for (; i + 1 < cnt; i += 2) {
      int s0 = sp[i], s1 = sp[i + 1];
      float2 f0 = *(const float2*)(fp + (size_t)s0 * 2);
      float2 f1 = *(const float2*)(fp + (size_t)s1 * 2);
      a0 += f0.x; a1 += f0.y;
      c0 += f1.x; c1 += f1.y;
    }
    if (i < cnt) {
      float2 f0 = *(const float2*)(fp + (size_t)sp[i] * 2);
      a0 += f0.x; a1 += f0.y;
    }
    float ri = rs_in[r * N + n];
    o0 += (a0 + c0) * ri + b2[r * 2 + 0];
    o1 += (a1 + c1) * ri + b2[r * 2 + 1];
  }
  *(float2*)(out + (size_t)n * 2) = make_float2(o0, o1);
}

extern "C" void kernel_launch(void* const* d_in, const int* in_sizes, int n_in,
                              void* d_out, int out_size, void* d_ws, size_t ws_size,
                              hipStream_t stream) {
  const float* x = (const float*)d_in[0];
  const int* edges = (const int*)d_in[1];
  const float* W1 = (const float*)d_in[2];
  const float* b1 = (const float*)d_in[3];
  const float* W2 = (const float*)d_in[4];
  const float* b2 = (const float*)d_in[5];
  float* out = (float*)d_out;

  const int N = in_sizes[0] / IN_F;          // 100000
  const int E = in_sizes[1] / (N_REL * 2);   // 1600000
  const int NS = (N + SB_SIZE - 1) >> SB_BITS;  // 49 super-buckets

  // workspace layout (256B aligned); stagings alias feat (build precedes use)
  char* ws = (char*)d_ws;
  size_t p = 0;
  auto take = [&](size_t b) { size_t o = p; p += (b + 255) & ~(size_t)255; return o; };
  size_t bcount2_off  = take((size_t)2 * N_REL * NSBMAX * 4);  // memset region
  size_t sbbase2_off  = take((size_t)2 * N_REL * NSBMAX * 4);
  size_t scursor2_off = take((size_t)2 * N_REL * NSBMAX * 4);
  size_t deg_in_off   = take((size_t)N_REL * N * 4);
  size_t rs_out_off   = take((size_t)N_REL * N * 4);
  size_t rs_in_off    = take((size_t)N_REL * N * 4);
  size_t offsets_off  = take((size_t)N_REL * N * 4);
  size_t csr_off      = take((size_t)N_REL * E * 4);
  size_t feat_off     = take((size_t)N * HID_F * 4);  // stagings alias this
  size_t h1_off       = take((size_t)N * HID_F * 4);
  size_t feat2_off    = take((size_t)N_REL * N * 2 * 4);
  (void)ws_size;

  unsigned* bcount2  = (unsigned*)(ws + bcount2_off);
  unsigned* sbbase2  = (unsigned*)(ws + sbbase2_off);
  unsigned* scursor2 = (unsigned*)(ws + scursor2_off);
  unsigned* deg_in   = (unsigned*)(ws + deg_in_off);
  float* rs_out = (float*)(ws + rs_out_off);
  float* rs_in  = (float*)(ws + rs_in_off);
  int* offsets  = (int*)(ws + offsets_off);
  int* csr_src  = (int*)(ws + csr_off);
  float* feat   = (float*)(ws + feat_off);
  // stagings alias the feat region: dst 19.2MB + src 9.6MB < 51.2MB
  unsigned* staging_dst = (unsigned*)(ws + feat_off);
  unsigned short* staging_src =
      (unsigned short*)(ws + feat_off + ((size_t)N_REL * E * 4 + 255 & ~(size_t)255));
  float* h1     = (float*)(ws + h1_off);
  float* feat2  = (float*)(ws + feat2_off);

  // zero bucket counters (tiny)
  hipMemsetAsync(ws + bcount2_off, 0, (size_t)2 * N_REL * NSBMAX * 4, stream);

  dim3 blk(256);
  HeteroGCN_count_kernel<<<dim3(512, N_REL), blk, 0, stream>>>(
      edges, bcount2, E, NS);
  HeteroGCN_scan_kernel<<<dim3(2 * N_REL), dim3(64), 0, stream>>>(
      bcount2, sbbase2, scursor2, NS);
  HeteroGCN_part_kernel<<<dim3((E + TILE - 1) / TILE, N_REL), blk, 0, stream>>>(
      edges, scursor2, staging_dst, staging_src, E, NS);
  HeteroGCN_build_kernel<<<dim3(NS, N_REL), blk, 0, stream>>>(
      staging_dst, sbbase2, bcount2, csr_src, offsets, deg_in, rs_in, N, E);
  HeteroGCN_degout_kernel<<<dim3(NS, N_REL), blk, 0, stream>>>(
      staging_src, sbbase2, bcount2, rs_out, N, E);

  // layer 1, relation by relation (feat buffer reused; stagings dead by now)
  for (int r = 0; r < N_REL; ++r) {
    HeteroGCN_gemm1_kernel<<<dim3((N + 63) / 64), blk, 0, stream>>>(
        x, W1 + (size_t)r * IN_F * HID_F, rs_out + (size_t)r * N, feat, N);
    HeteroGCN_agg1_kernel<<<dim3((N + 1) / 2), blk, 0, stream>>>(
        feat, csr_src + (size_t)r * E, offsets + (size_t)r * N,
        deg_in + (size_t)r * N, rs_in + (size_t)r * N, b1, h1, N, r);
  }

  // layer 2
  HeteroGCN_gemm2_kernel<<<dim3((N * 64 + 255) / 256), blk, 0, stream>>>(
      h1, W2, rs_out, feat2, N);
  HeteroGCN_agg2_kernel<<<dim3((N + 255) / 256), blk, 0, stream>>>(
      feat2, csr_src, offsets, deg_in, rs_in, b2, out, N, E);
}

// Round 10
// 903.275 us; speedup vs baseline: 1.9879x; 1.2312x over previous
//
#include <hip/hip_runtime.h>
#include <hip/hip_bf16.h>

// HeteroGCN: 2-layer, 3-relation GraphConv (norm='both') on MI355X.
// Build phase (all scatter/histogram work LDS-local; global writes coalesced —
// measured: random 4B global atomics/stores cost ~32B HBM write-through each):
//   K1 count:  LDS 49-bin hist of dst>>11 AND src>>11 (no per-node atomics)
//   K2 scan2:  exclusive prefix of 6 bucket-count rows (dst x3, src x3)
//   K3 part:   per 2048-edge tile: LDS multisplit on BOTH keys; coalesced
//              staging writes (dst: src<<11|dst&2047 u32; src: src&2047 u16)
//   K4 build:  per dst-super-bucket: LDS hist+scan -> offsets/deg_in/rs_in;
//              scatter src into contiguous L2-resident CSR segment
//   K5 degout: per src-super-bucket: LDS hist -> rs_out (coalesced write)
// Layer phase:
//   per r: GEMM1 (x @ W1[r]) * rs_out -> feat_r (bf16 store; halves gather BW)
//   AGG1 fused: wave/node, gather 3 relations from bf16 feat, rs_in scale,
//               +bias sum, ReLU -> h1 (fp32, written once)
//   GEMM2 (wave/node) -> feat2 ; AGG2 gather + bias -> out

#define N_REL 3
#define IN_F 256
#define HID_F 128
#define SB_BITS 11
#define SB_SIZE 2048   // nodes per super-bucket
#define NSBMAX 64      // ceil(100000/2048)=49 <= 64
#define TILE 2048      // edges per part-tile

__device__ __forceinline__ unsigned short f2bf(float x) {  // RNE f32->bf16
  unsigned u = __float_as_uint(x);
  return (unsigned short)((u + 0x7fffu + ((u >> 16) & 1u)) >> 16);
}
__device__ __forceinline__ float2 bf2f(unsigned u) {  // packed bf16x2 -> f32x2
  float2 f;
  f.x = __uint_as_float(u << 16);
  f.y = __uint_as_float(u & 0xffff0000u);
  return f;
}

// ---------------- K1: dual 49-bin bucket count (dst + src) ----------------
__global__ __launch_bounds__(256) void HeteroGCN_count_kernel(
    const int* __restrict__ edges, unsigned* __restrict__ bcount2,
    int E, int NS) {
  __shared__ unsigned hd[NSBMAX];
  __shared__ unsigned hs[NSBMAX];
  int r = blockIdx.y;
  if (threadIdx.x < NSBMAX) { hd[threadIdx.x] = 0u; hs[threadIdx.x] = 0u; }
  __syncthreads();
  const int* ep = edges + (size_t)r * 2 * E;
  int stride = gridDim.x * 256;
  for (int e = blockIdx.x * 256 + threadIdx.x; e < E; e += stride) {
    int src = ep[e];
    int dst = ep[E + e];
    atomicAdd(&hd[dst >> SB_BITS], 1u);
    atomicAdd(&hs[src >> SB_BITS], 1u);
  }
  __syncthreads();
  if (threadIdx.x < (unsigned)NS) {
    unsigned h = hd[threadIdx.x];
    if (h) atomicAdd(&bcount2[r * NSBMAX + threadIdx.x], h);
    h = hs[threadIdx.x];
    if (h) atomicAdd(&bcount2[(N_REL + r) * NSBMAX + threadIdx.x], h);
  }
}

// ---------------- K2: exclusive scan of 6 bucket-count rows ----------------
__global__ __launch_bounds__(64) void HeteroGCN_scan_kernel(
    const unsigned* __restrict__ bcount2, unsigned* __restrict__ sbbase2,
    unsigned* __restrict__ scursor2, int NS) {
  int row = blockIdx.x;  // 0..2*N_REL-1
  int t = threadIdx.x;
  unsigned v = (t < NS) ? bcount2[row * NSBMAX + t] : 0u;
  unsigned pre = v;
  #pragma unroll
  for (int d = 1; d < 64; d <<= 1) {
    unsigned tt = __shfl_up(pre, (unsigned)d, 64);
    if (t >= d) pre += tt;
  }
  if (t < NS) {
    sbbase2[row * NSBMAX + t] = pre - v;
    scursor2[row * NSBMAX + t] = pre - v;
  }
}

// ---------------- K3: tile-sort partition into dst + src stagings ----------------
__global__ __launch_bounds__(256) void HeteroGCN_part_kernel(
    const int* __restrict__ edges, unsigned* __restrict__ scursor2,
    unsigned* __restrict__ staging_dst, unsigned short* __restrict__ staging_src,
    int E, int NS) {
  __shared__ unsigned hd[NSBMAX], hs[NSBMAX];
  __shared__ unsigned toffd[NSBMAX], toffs[NSBMAX];
  __shared__ unsigned gbd[NSBMAX], gbs[NSBMAX];
  __shared__ unsigned ordb[TILE];
  __shared__ unsigned addrb[TILE];
  __shared__ unsigned short srcw[TILE];
  __shared__ unsigned saddr[TILE];
  int r = blockIdx.y;
  const int* ep = edges + (size_t)r * 2 * E;
  int t0 = blockIdx.x * TILE;
  int nt = min(TILE, E - t0);
  if (threadIdx.x < NSBMAX) { hd[threadIdx.x] = 0u; hs[threadIdx.x] = 0u; }
  __syncthreads();
  int sbk[8];
  unsigned rkk[8], pkk[8], rks[8];
  #pragma unroll 8
  for (int k = 0; k < 8; ++k) {
    int ii = k * 256 + (int)threadIdx.x;
    sbk[k] = -1;
    if (ii < nt) {
      int i = t0 + ii;
      int src = ep[i];
      int dst = ep[E + i];
      int sb = dst >> SB_BITS;
      rkk[k] = atomicAdd(&hd[sb], 1u);
      rks[k] = atomicAdd(&hs[src >> SB_BITS], 1u);
      pkk[k] = ((unsigned)src << SB_BITS) | ((unsigned)dst & (SB_SIZE - 1u));
      sbk[k] = sb;
    }
  }
  __syncthreads();
  {
    int w = threadIdx.x >> 6, l = threadIdx.x & 63;
    if (w < 2) {
      unsigned* hh = w ? hs : hd;
      unsigned* tf = w ? toffs : toffd;
      unsigned* gb = w ? gbs : gbd;
      int row = w ? (N_REL + r) : r;
      unsigned v = (l < NS) ? hh[l] : 0u;
      unsigned pre = v;
      #pragma unroll
      for (int d = 1; d < 64; d <<= 1) {
        unsigned tt = __shfl_up(pre, (unsigned)d, 64);
        if (l >= d) pre += tt;
      }
      if (l < NS) {
        tf[l] = pre - v;
        gb[l] = v ? atomicAdd(&scursor2[row * NSBMAX + l], v) : 0u;
      }
    }
  }
  __syncthreads();
  #pragma unroll 8
  for (int k = 0; k < 8; ++k) {
    if (sbk[k] >= 0) {
      unsigned pos = toffd[sbk[k]] + rkk[k];
      ordb[pos] = pkk[k];
      addrb[pos] = gbd[sbk[k]] + rkk[k];
      int sb2 = (int)(pkk[k] >> 22);          // src >> 11
      unsigned pos2 = toffs[sb2] + rks[k];
      srcw[pos2] = (unsigned short)((pkk[k] >> SB_BITS) & (SB_SIZE - 1u));
      saddr[pos2] = gbs[sb2] + rks[k];
    }
  }
  __syncthreads();
  unsigned* stg = staging_dst + (size_t)r * E;
  unsigned short* sst = staging_src + (size_t)r * E;
  for (int ii = threadIdx.x; ii < nt; ii += 256) {
    stg[addrb[ii]] = ordb[ii];   // piecewise-consecutive addresses
    sst[saddr[ii]] = srcw[ii];
  }
}

// ---------------- K4: per-dst-super-bucket CSR build + node metadata ----------
__global__ __launch_bounds__(256) void HeteroGCN_build_kernel(
    const unsigned* __restrict__ staging_dst, const unsigned* __restrict__ sbbase2,
    const unsigned* __restrict__ bcount2, int* __restrict__ csr_src,
    int* __restrict__ offsets, unsigned* __restrict__ deg_in,
    float* __restrict__ rs_in, int N, int E) {
  __shared__ unsigned hist[SB_SIZE];  // histogram -> exclusive offsets -> cursors
  __shared__ unsigned wtot[4];
  int s = blockIdx.x;
  int r = blockIdx.y;
  int tid = threadIdx.x;
  int lane = tid & 63;
  int wid = tid >> 6;
  unsigned base = sbbase2[r * NSBMAX + s];
  unsigned cnt = bcount2[r * NSBMAX + s];
  for (int i = tid; i < SB_SIZE; i += 256) hist[i] = 0u;
  __syncthreads();
  const unsigned* sp = staging_dst + (size_t)r * E + base;
  for (unsigned i = tid; i < cnt; i += 256)
    atomicAdd(&hist[sp[i] & (SB_SIZE - 1u)], 1u);
  __syncthreads();
  // block exclusive scan over hist[2048], 8 values per thread
  unsigned v[8], lsum = 0;
  #pragma unroll 8
  for (int k = 0; k < 8; ++k) {
    v[k] = hist[tid * 8 + k];
    lsum += v[k];
  }
  unsigned pre = lsum;
  #pragma unroll
  for (int d = 1; d < 64; d <<= 1) {
    unsigned tt = __shfl_up(pre, (unsigned)d, 64);
    if (lane >= d) pre += tt;
  }
  if (lane == 63) wtot[wid] = pre;
  __syncthreads();
  unsigned woff = 0;
  for (int w = 0; w < wid; ++w) woff += wtot[w];
  unsigned run = woff + pre - lsum;  // exclusive offset of this thread's first node
  #pragma unroll 8
  for (int k = 0; k < 8; ++k) {
    int node = s * SB_SIZE + tid * 8 + k;
    if (node < N) {
      size_t gi = (size_t)r * N + node;
      deg_in[gi] = v[k];
      rs_in[gi] = rsqrtf((float)max(v[k], 1u));
      offsets[gi] = (int)(base + run);
    }
    hist[tid * 8 + k] = run;  // becomes scatter cursor
    run += v[k];
  }
  __syncthreads();
  int* cp = csr_src + (size_t)r * E + base;
  for (unsigned i = tid; i < cnt; i += 256) {
    unsigned rec = sp[i];
    unsigned slot = atomicAdd(&hist[rec & (SB_SIZE - 1u)], 1u);
    cp[slot] = (int)(rec >> SB_BITS);  // contiguous L2-resident segment
  }
}

// ---------------- K5: per-src-super-bucket deg_out histogram -> rs_out --------
__global__ __launch_bounds__(256) void HeteroGCN_degout_kernel(
    const unsigned short* __restrict__ staging_src,
    const unsigned* __restrict__ sbbase2, const unsigned* __restrict__ bcount2,
    float* __restrict__ rs_out, int N, int E) {
  __shared__ unsigned hist[SB_SIZE];
  int s = blockIdx.x;
  int r = blockIdx.y;
  int tid = threadIdx.x;
  unsigned base = sbbase2[(N_REL + r) * NSBMAX + s];
  unsigned cnt = bcount2[(N_REL + r) * NSBMAX + s];
  for (int i = tid; i < SB_SIZE; i += 256) hist[i] = 0u;
  __syncthreads();
  const unsigned short* sp = staging_src + (size_t)r * E + base;
  for (unsigned i = tid; i < cnt; i += 256) atomicAdd(&hist[sp[i]], 1u);
  __syncthreads();
  for (int i = tid; i < SB_SIZE; i += 256) {
    int node = s * SB_SIZE + i;
    if (node < N)
      rs_out[(size_t)r * N + node] = rsqrtf((float)max(hist[i], 1u));
  }
}

// ---------------- GEMM1: feat = bf16((x @ W) * rs_out), M x 256 @ 256 x 128 ----
__global__ __launch_bounds__(256) void HeteroGCN_gemm1_kernel(
    const float* __restrict__ x, const float* __restrict__ W,
    const float* __restrict__ rs_out, unsigned short* __restrict__ feat, int M) {
  __shared__ float As[64][68];
  __shared__ float Bs[64][128];
  int tid = threadIdx.x;
  int block_row = blockIdx.x * 64;
  int rg = tid >> 4;
  int cg = tid & 15;
  int row0 = rg * 4;
  int colA = cg * 4;
  float acc[4][8] = {};
  for (int k0 = 0; k0 < IN_F; k0 += 64) {
    #pragma unroll
    for (int i = 0; i < 4; ++i) {
      int f4 = tid + i * 256;
      int rr = f4 >> 4;
      int cc = (f4 & 15) << 2;
      int grow = block_row + rr;
      float4 vv = make_float4(0.f, 0.f, 0.f, 0.f);
      if (grow < M) vv = *(const float4*)(x + (size_t)grow * IN_F + k0 + cc);
      *(float4*)(&As[rr][cc]) = vv;
    }
    #pragma unroll
    for (int i = 0; i < 8; ++i) {
      int f4 = tid + i * 256;
      int rr = f4 >> 5;
      int cc = (f4 & 31) << 2;
      *(float4*)(&Bs[rr][cc]) = *(const float4*)(W + (size_t)(k0 + rr) * HID_F + cc);
    }
    __syncthreads();
    #pragma unroll
    for (int kk = 0; kk < 64; ++kk) {
      float a[4];
      #pragma unroll
      for (int i = 0; i < 4; ++i) a[i] = As[row0 + i][kk];
      float4 b0 = *(const float4*)(&Bs[kk][colA]);
      float4 b1 = *(const float4*)(&Bs[kk][64 + colA]);
      #pragma unroll
      for (int i = 0; i < 4; ++i) {
        acc[i][0] += a[i] * b0.x; acc[i][1] += a[i] * b0.y;
        acc[i][2] += a[i] * b0.z; acc[i][3] += a[i] * b0.w;
        acc[i][4] += a[i] * b1.x; acc[i][5] += a[i] * b1.y;
        acc[i][6] += a[i] * b1.z; acc[i][7] += a[i] * b1.w;
      }
    }
    __syncthreads();
  }
  #pragma unroll
  for (int i = 0; i < 4; ++i) {
    int grow = block_row + row0 + i;
    if (grow < M) {
      float s = rs_out[grow];
      ushort4 v0, v1;
      v0.x = f2bf(acc[i][0] * s); v0.y = f2bf(acc[i][1] * s);
      v0.z = f2bf(acc[i][2] * s); v0.w = f2bf(acc[i][3] * s);
      v1.x = f2bf(acc[i][4] * s); v1.y = f2bf(acc[i][5] * s);
      v1.z = f2bf(acc[i][6] * s); v1.w = f2bf(acc[i][7] * s);
      *(ushort4*)(feat + (size_t)grow * HID_F + colA) = v0;
      *(ushort4*)(feat + (size_t)grow * HID_F + 64 + colA) = v1;
    }
  }
}

// ---------------- AGG1 fused: h1 = relu(sum_r rs_in_r * gather(feat_r) + bsum) --
// wave per node; lane owns feature pair (2*lane, 2*lane+1); MLP=4 rows in flight.
__global__ __launch_bounds__(256) void HeteroGCN_agg1_kernel(
    const unsigned short* __restrict__ feat0,
    const unsigned short* __restrict__ feat1,
    const unsigned short* __restrict__ feat2b,
    const int* __restrict__ csr, const int* __restrict__ offsets,
    const unsigned* __restrict__ deg_in, const float* __restrict__ rs_in,
    const float* __restrict__ b1, float* __restrict__ h1, int N, int E) {
  int w = threadIdx.x >> 6;
  int lane = threadIdx.x & 63;
  int n = blockIdx.x * 4 + w;
  if (n >= N) return;
  float hx = 0.f, hy = 0.f;
  #pragma unroll
  for (int r = 0; r < 3; ++r) {
    const unsigned short* fp = (r == 0) ? feat0 : (r == 1) ? feat1 : feat2b;
    int off = offsets[r * N + n];
    int cnt = (int)deg_in[r * N + n];
    const int* sp = csr + (size_t)r * E + off;
    float a0 = 0.f, a1 = 0.f, b0 = 0.f, bb1 = 0.f;
    float c0 = 0.f, c1 = 0.f, d0 = 0.f, d1 = 0.f;
    int i = 0;
    for (; i + 3 < cnt; i += 4) {
      int s0 = sp[i], s1 = sp[i + 1], s2 = sp[i + 2], s3 = sp[i + 3];
      unsigned u0 = *(const unsigned*)(fp + (size_t)s0 * HID_F + lane * 2);
      unsigned u1 = *(const unsigned*)(fp + (size_t)s1 * HID_F + lane * 2);
      unsigned u2 = *(const unsigned*)(fp + (size_t)s2 * HID_F + lane * 2);
      unsigned u3 = *(const unsigned*)(fp + (size_t)s3 * HID_F + lane * 2);
      float2 v0 = bf2f(u0), v1 = bf2f(u1), v2 = bf2f(u2), v3 = bf2f(u3);
      a0 += v0.x; a1 += v0.y;
      b0 += v1.x; bb1 += v1.y;
      c0 += v2.x; c1 += v2.y;
      d0 += v3.x; d1 += v3.y;
    }
    for (; i < cnt; ++i) {
      unsigned u = *(const unsigned*)(fp + (size_t)sp[i] * HID_F + lane * 2);
      float2 v = bf2f(u);
      a0 += v.x; a1 += v.y;
    }
    float ri = rs_in[r * N + n];
    hx += ((a0 + b0) + (c0 + d0)) * ri;
    hy += ((a1 + bb1) + (c1 + d1)) * ri;
  }
  int f = lane * 2;
  float bs0 = b1[f] + b1[HID_F + f] + b1[2 * HID_F + f];
  float bs1 = b1[f + 1] + b1[HID_F + f + 1] + b1[2 * HID_F + f + 1];
  float2 o;
  o.x = fmaxf(hx + bs0, 0.f);
  o.y = fmaxf(hy + bs1, 0.f);
  *(float2*)(h1 + (size_t)n * HID_F + f) = o;
}

// ---------------- GEMM2: feat2[r][n][c] = (h1[n].W2[r][:,c]) * rs_out[r][n] ----
__global__ __launch_bounds__(256) void HeteroGCN_gemm2_kernel(
    const float* __restrict__ h1, const float* __restrict__ W2,
    const float* __restrict__ rs_out, float* __restrict__ feat2, int N) {
  int wid = (blockIdx.x * blockDim.x + threadIdx.x) >> 6;
  int lane = threadIdx.x & 63;
  if (wid >= N) return;
  float2 h = *(const float2*)(h1 + (size_t)wid * HID_F + lane * 2);
  float p[6];
  #pragma unroll
  for (int r = 0; r < 3; ++r) {
    #pragma unroll
    for (int c = 0; c < 2; ++c) {
      float w0 = W2[((size_t)r * HID_F + lane * 2) * 2 + c];
      float w1 = W2[((size_t)r * HID_F + lane * 2 + 1) * 2 + c];
      p[r * 2 + c] = h.x * w0 + h.y * w1;
    }
  }
  #pragma unroll
  for (int o = 32; o > 0; o >>= 1) {
    #pragma unroll
    for (int q = 0; q < 6; ++q) p[q] += __shfl_xor(p[q], o, 64);
  }
  if (lane == 0) {
    #pragma unroll
    for (int q = 0; q < 6; ++q) {
      int r = q >> 1, c = q & 1;
      feat2[((size_t)r * N + wid) * 2 + c] = p[q] * rs_out[r * N + wid];
    }
  }
}

// ---------------- AGG2: out[n][c] = sum_r rs_in * sum_src feat2 + bias ---------
__global__ __launch_bounds__(256) void HeteroGCN_agg2_kernel(
    const float* __restrict__ feat2, const int* __restrict__ csr_src,
    const int* __restrict__ offsets, const unsigned* __restrict__ deg_in,
    const float* __restrict__ rs_in, const float* __restrict__ b2,
    float* __restrict__ out, int N, int E) {
  int n = blockIdx.x * blockDim.x + threadIdx.x;
  if (n >= N) return;
  float o0 = 0.f, o1 = 0.f;
  #pragma unroll
  for (int r = 0; r < 3; ++r) {
    int off = offsets[r * N + n];
    int cnt = (int)deg_in[r * N + n];
    const int* sp = csr_src + (size_t)r * E + off;
    const float* fp = feat2 + (size_t)r * N * 2;
    float a0 = 0.f, a1 = 0.f, c0 = 0.f, c1 = 0.f;
    int i = 0;
    for (; i + 1 < cnt; i += 2) {
      int s0 = sp[i], s1 = sp[i + 1];
      float2 f0 = *(const float2*)(fp + (size_t)s0 * 2);
      float2 f1 = *(const float2*)(fp + (size_t)s1 * 2);
      a0 += f0.x; a1 += f0.y;
      c0 += f1.x; c1 += f1.y;
    }
    if (i < cnt) {
      float2 f0 = *(const float2*)(fp + (size_t)sp[i] * 2);
      a0 += f0.x; a1 += f0.y;
    }
    float ri = rs_in[r * N + n];
    o0 += (a0 + c0) * ri + b2[r * 2 + 0];
    o1 += (a1 + c1) * ri + b2[r * 2 + 1];
  }
  *(float2*)(out + (size_t)n * 2) = make_float2(o0, o1);
}

extern "C" void kernel_launch(void* const* d_in, const int* in_sizes, int n_in,
                              void* d_out, int out_size, void* d_ws, size_t ws_size,
                              hipStream_t stream) {
  const float* x = (const float*)d_in[0];
  const int* edges = (const int*)d_in[1];
  const float* W1 = (const float*)d_in[2];
  const float* b1 = (const float*)d_in[3];
  const float* W2 = (const float*)d_in[4];
  const float* b2 = (const float*)d_in[5];
  float* out = (float*)d_out;

  const int N = in_sizes[0] / IN_F;          // 100000
  const int E = in_sizes[1] / (N_REL * 2);   // 1600000
  const int NS = (N + SB_SIZE - 1) >> SB_BITS;  // 49 super-buckets

  // workspace layout (256B aligned); stagings alias feat3 (build precedes use)
  char* ws = (char*)d_ws;
  size_t p = 0;
  auto take = [&](size_t b) { size_t o = p; p += (b + 255) & ~(size_t)255; return o; };
  size_t bcount2_off  = take((size_t)2 * N_REL * NSBMAX * 4);  // memset region
  size_t sbbase2_off  = take((size_t)2 * N_REL * NSBMAX * 4);
  size_t scursor2_off = take((size_t)2 * N_REL * NSBMAX * 4);
  size_t deg_in_off   = take((size_t)N_REL * N * 4);
  size_t rs_out_off   = take((size_t)N_REL * N * 4);
  size_t rs_in_off    = take((size_t)N_REL * N * 4);
  size_t offsets_off  = take((size_t)N_REL * N * 4);
  size_t csr_off      = take((size_t)N_REL * E * 4);
  size_t feat3_off    = take((size_t)N_REL * N * HID_F * 2);  // bf16 x3 (76.8MB)
  size_t h1_off       = take((size_t)N * HID_F * 4);
  size_t feat2_off    = take((size_t)N_REL * N * 2 * 4);
  (void)ws_size;

  unsigned* bcount2  = (unsigned*)(ws + bcount2_off);
  unsigned* sbbase2  = (unsigned*)(ws + sbbase2_off);
  unsigned* scursor2 = (unsigned*)(ws + scursor2_off);
  unsigned* deg_in   = (unsigned*)(ws + deg_in_off);
  float* rs_out = (float*)(ws + rs_out_off);
  float* rs_in  = (float*)(ws + rs_in_off);
  int* offsets  = (int*)(ws + offsets_off);
  int* csr_src  = (int*)(ws + csr_off);
  unsigned short* feat3 = (unsigned short*)(ws + feat3_off);
  // stagings alias the feat3 region: dst 19.2MB + src 9.6MB < 76.8MB
  unsigned* staging_dst = (unsigned*)(ws + feat3_off);
  unsigned short* staging_src =
      (unsigned short*)(ws + feat3_off + (((size_t)N_REL * E * 4 + 255) & ~(size_t)255));
  float* h1     = (float*)(ws + h1_off);
  float* feat2  = (float*)(ws + feat2_off);

  // zero bucket counters (tiny)
  hipMemsetAsync(ws + bcount2_off, 0, (size_t)2 * N_REL * NSBMAX * 4, stream);

  dim3 blk(256);
  HeteroGCN_count_kernel<<<dim3(512, N_REL), blk, 0, stream>>>(
      edges, bcount2, E, NS);
  HeteroGCN_scan_kernel<<<dim3(2 * N_REL), dim3(64), 0, stream>>>(
      bcount2, sbbase2, scursor2, NS);
  HeteroGCN_part_kernel<<<dim3((E + TILE - 1) / TILE, N_REL), blk, 0, stream>>>(
      edges, scursor2, staging_dst, staging_src, E, NS);
  HeteroGCN_build_kernel<<<dim3(NS, N_REL), blk, 0, stream>>>(
      staging_dst, sbbase2, bcount2, csr_src, offsets, deg_in, rs_in, N, E);
  HeteroGCN_degout_kernel<<<dim3(NS, N_REL), blk, 0, stream>>>(
      staging_src, sbbase2, bcount2, rs_out, N, E);

  // layer 1: 3x GEMM into bf16 feat buffers (stagings dead after degout)
  for (int r = 0; r < N_REL; ++r) {
    HeteroGCN_gemm1_kernel<<<dim3((N + 63) / 64), blk, 0, stream>>>(
        x, W1 + (size_t)r * IN_F * HID_F, rs_out + (size_t)r * N,
        feat3 + (size_t)r * N * HID_F, N);
  }
  // fused aggregation: one pass over all 3 relations
  HeteroGCN_agg1_kernel<<<dim3((N + 3) / 4), blk, 0, stream>>>(
      feat3, feat3 + (size_t)N * HID_F, feat3 + (size_t)2 * N * HID_F,
      csr_src, offsets, deg_in, rs_in, b1, h1, N, E);

  // layer 2
  HeteroGCN_gemm2_kernel<<<dim3((N * 64 + 255) / 256), blk, 0, stream>>>(
      h1, W2, rs_out, feat2, N);
  HeteroGCN_agg2_kernel<<<dim3((N + 255) / 256), blk, 0, stream>>>(
      feat2, csr_src, offsets, deg_in, rs_in, b2, out, N, E);
}